// Round 1
// baseline (88.709 us; speedup 1.0000x reference)
//
#include <hip/hip_runtime.h>

#define NEG_INF -1000000000.0f
#define LEAKY 0.2f

constexpr int B = 4, H = 8, N = 256, D = 64;
constexpr int QBLK = 8;
constexpr int PATTN_OFF = B * H * N * D;   // 524288

// Kernel 1: qp[bhn,e] = sum_d q[bhn,d] * W_h[e,d]
//           kpb[bhn,e] = sum_d k[bhn,d] * W_h[e,64+d] + b_h[e]
__global__ __launch_bounds__(256) void proj_kernel(
    const float* __restrict__ q, const float* __restrict__ k,
    const float* __restrict__ W_h, const float* __restrict__ b_h,
    float* __restrict__ qp, float* __restrict__ kpb)
{
    __shared__ float q_s[4][64];
    __shared__ float k_s[4][64];
    int t = threadIdx.x;
    int r = t >> 6, e = t & 63;
    int base = blockIdx.x * 4;          // row index into (B*H*N)
    q_s[r][e] = q[base * 64 + t];
    k_s[r][e] = k[base * 64 + t];
    __syncthreads();
    const float* wq = W_h + e * 128;    // W_h[e, 0:64]
    const float* wk = wq + 64;          // W_h[e, 64:128]
    float accq = 0.f, acck = 0.f;
    #pragma unroll
    for (int d0 = 0; d0 < 64; ++d0) {
        accq = fmaf(q_s[r][d0], wq[d0], accq);
        acck = fmaf(k_s[r][d0], wk[d0], acck);
    }
    qp[base * 64 + t] = accq;
    kpb[base * 64 + t] = acck + b_h[e];
}

// Kernel 2: per (b,h, 8 q-rows): scores -> mask -> softmax -> p_attn, PV
__global__ __launch_bounds__(256) void attn_kernel(
    const float* __restrict__ qp, const float* __restrict__ kpb,
    const float* __restrict__ V, const int* __restrict__ mask,
    const float* __restrict__ W_o, const float* __restrict__ b_o,
    float* __restrict__ out)
{
    __shared__ float kpT[64 * 257];     // [e][m], stride 257 -> bank (e+m)%32
    __shared__ float qrows[QBLK][64];
    __shared__ float Wo_s[64];
    __shared__ float p_s[256];
    __shared__ float red_max[4];
    __shared__ float red_sum[4];
    __shared__ float pv_part[256];      // [mc][d]

    int t = threadIdx.x;
    int lane = t & 63, wid = t >> 6;
    int bh = blockIdx.x >> 5;           // 32 blocks per (b,h)
    int nb = blockIdx.x & 31;
    int b = bh >> 3;                    // H = 8
    int n0 = nb * QBLK;
    int kbase = bh * N * 64;

    // stage kpb tile transposed: kpT[e*257+m] = kpb[bh, m, e]
    #pragma unroll 8
    for (int i = 0; i < 64; ++i) {
        int idx = t + i * 256;
        int m = idx >> 6, e = idx & 63;
        kpT[e * 257 + m] = kpb[kbase + idx];
    }
    if (t < 64) Wo_s[t] = W_o[t];
    for (int i = t; i < QBLK * 64; i += 256)
        qrows[i >> 6][i & 63] = qp[kbase + n0 * 64 + i];
    float b_o_v = b_o[0];
    __syncthreads();

    for (int r = 0; r < QBLK; ++r) {
        int n = n0 + r;
        // ---- score for column m = t ----
        float s = b_o_v;
        #pragma unroll
        for (int e = 0; e < 64; ++e) {
            float hv = qrows[r][e] + kpT[e * 257 + t];
            hv = hv > 0.f ? hv : LEAKY * hv;
            s = fmaf(Wo_s[e], hv, s);
        }
        int mv = mask[(b * N + n) * N + t];
        if (mv == 0) s = NEG_INF;

        // ---- block softmax over 256 scores ----
        float v = s;
        #pragma unroll
        for (int off = 32; off > 0; off >>= 1) v = fmaxf(v, __shfl_xor(v, off, 64));
        if (lane == 0) red_max[wid] = v;
        __syncthreads();
        v = fmaxf(fmaxf(red_max[0], red_max[1]), fmaxf(red_max[2], red_max[3]));
        float p = __expf(s - v);
        float ssum = p;
        #pragma unroll
        for (int off = 32; off > 0; off >>= 1) ssum += __shfl_xor(ssum, off, 64);
        if (lane == 0) red_sum[wid] = ssum;
        __syncthreads();
        ssum = red_sum[0] + red_sum[1] + red_sum[2] + red_sum[3];
        float pn = p / ssum;
        p_s[t] = pn;
        out[PATTN_OFF + (bh * N + n) * N + t] = pn;   // p_attn output
        __syncthreads();

        // ---- PV: out[n,d] = sum_m p[m] * V[bh,m,d] ----
        int d = t & 63, mc = t >> 6;
        const float* Vp = V + kbase + mc * 64 * 64 + d;
        float acc = 0.f;
        #pragma unroll
        for (int j = 0; j < 64; ++j)
            acc = fmaf(p_s[mc * 64 + j], Vp[j * 64], acc);
        pv_part[t] = acc;
        __syncthreads();
        if (t < 64) {
            float o = pv_part[t] + pv_part[64 + t] + pv_part[128 + t] + pv_part[192 + t];
            out[(bh * N + n) * 64 + t] = o;
        }
        __syncthreads();
    }
}

extern "C" void kernel_launch(void* const* d_in, const int* in_sizes, int n_in,
                              void* d_out, int out_size, void* d_ws, size_t ws_size,
                              hipStream_t stream) {
    const float* q    = (const float*)d_in[0];
    const float* k    = (const float*)d_in[1];
    const float* v    = (const float*)d_in[2];
    const int*   mask = (const int*)d_in[3];
    const float* W_h  = (const float*)d_in[4];
    const float* b_h  = (const float*)d_in[5];
    const float* W_o  = (const float*)d_in[6];
    const float* b_o  = (const float*)d_in[7];
    float* out = (float*)d_out;

    float* qp  = (float*)d_ws;                 // B*H*N*D floats
    float* kpb = qp + B * H * N * D;           // B*H*N*D floats

    proj_kernel<<<B * H * N / 4, 256, 0, stream>>>(q, k, W_h, b_h, qp, kpb);
    attn_kernel<<<B * H * (N / QBLK), 256, 0, stream>>>(qp, kpb, v, mask, W_o, b_o, out);
}

// Round 2
// 60.386 us; speedup vs baseline: 1.4690x; 1.4690x over previous
//
#include <hip/hip_runtime.h>

#define NEG_INF -1000000000.0f

constexpr int B = 4, H = 8, N = 256, D = 64;
constexpr int QBLK = 8;
constexpr int PATTN_OFF = B * H * N * D;   // 524288
constexpr int NROWS = B * H * N;           // 8192

// ws layout (floats): qp[NROWS*64] | kpb[NROWS*64] | cq6[NROWS] | ck6[NROWS] | w4[64]

// proj: qp[r,e] = sum_d q[r,d]*W_h[e,d]
//       kpb[r,e] = sum_d k[r,d]*W_h[e,64+d] + b_h[e]
//       cq6[r] = 0.6*sum_e Wo[e]*qp[r,e] + b_o ;  ck6[r] = 0.6*sum_e Wo[e]*kpb[r,e]
//       w4[e] = 0.4*Wo[e]
__global__ __launch_bounds__(256) void proj_kernel(
    const float* __restrict__ q, const float* __restrict__ k,
    const float* __restrict__ W_h, const float* __restrict__ b_h,
    const float* __restrict__ W_o, const float* __restrict__ b_o,
    float* __restrict__ qp, float* __restrict__ kpb,
    float* __restrict__ cq6, float* __restrict__ ck6, float* __restrict__ w4)
{
    __shared__ float WT[128 * 65];   // WT[d][e] = W_h[e][d], stride 65 -> bank (d+e)%32
    int t = threadIdx.x;
    int lane = t & 63;
    int wid = __builtin_amdgcn_readfirstlane(t >> 6);

    // stage W_h transposed (8192 floats = 2048 float4, 256 threads x 8)
    #pragma unroll
    for (int i = 0; i < 8; ++i) {
        int fidx = (t + i * 256) * 4;
        float4 w = *reinterpret_cast<const float4*>(W_h + fidx);
        int e = fidx >> 7, d = fidx & 127;
        WT[(d + 0) * 65 + e] = w.x;
        WT[(d + 1) * 65 + e] = w.y;
        WT[(d + 2) * 65 + e] = w.z;
        WT[(d + 3) * 65 + e] = w.w;
    }
    if (blockIdx.x == 0 && t < 64) w4[t] = 0.4f * W_o[t];
    __syncthreads();

    int rbase = blockIdx.x * 32 + wid * 8;   // this thread: 8 rows, e = lane
    float accq[8] = {}, acck[8] = {};
    float wq[32], wk[32];
    #pragma unroll
    for (int half = 0; half < 2; ++half) {
        int d0 = half * 32;
        #pragma unroll
        for (int d = 0; d < 32; ++d) {
            wq[d] = WT[(d0 + d) * 65 + lane];
            wk[d] = WT[(64 + d0 + d) * 65 + lane];
        }
        #pragma unroll
        for (int j = 0; j < 8; ++j) {
            const float* qrow = q + (rbase + j) * 64 + d0;   // uniform -> s_load
            const float* krow = k + (rbase + j) * 64 + d0;
            #pragma unroll
            for (int d = 0; d < 32; ++d) {
                accq[j] = fmaf(qrow[d], wq[d], accq[j]);
                acck[j] = fmaf(krow[d], wk[d], acck[j]);
            }
        }
    }
    float bh_e = b_h[lane];
    float wo = W_o[lane];
    float bo = b_o[0];
    #pragma unroll
    for (int j = 0; j < 8; ++j) {
        float aq = accq[j];
        float ak = acck[j] + bh_e;
        qp[(rbase + j) * 64 + lane] = aq;
        kpb[(rbase + j) * 64 + lane] = ak;
        float sq = wo * aq, sk = wo * ak;
        #pragma unroll
        for (int off = 32; off > 0; off >>= 1) {
            sq += __shfl_xor(sq, off, 64);
            sk += __shfl_xor(sk, off, 64);
        }
        if (lane == 0) {
            cq6[rbase + j] = 0.6f * sq + bo;
            ck6[rbase + j] = 0.6f * sk;
        }
    }
}

// attn: block = (b,h, 8 q-rows); thread t owns column m=t (kpb row t in VGPRs)
__global__ __launch_bounds__(256) void attn_kernel(
    const float* __restrict__ qp, const float* __restrict__ kpb,
    const float* __restrict__ V, const int* __restrict__ mask,
    const float* __restrict__ cq6, const float* __restrict__ ck6,
    const float* __restrict__ w4g,
    float* __restrict__ out)
{
    __shared__ float smem[QBLK * 256];   // p tile, then PV partials
    __shared__ float2 red[2][4];

    int t = threadIdx.x;
    int lane = t & 63;
    int wid = __builtin_amdgcn_readfirstlane(t >> 6);
    int bh = blockIdx.x >> 5;
    int nb = blockIdx.x & 31;
    int b = bh >> 3;
    int n0 = nb * QBLK;
    int kvbase = bh * N * 64;

    // kpb row t -> 64 VGPRs
    float kv[64];
    const float4* kp4 = reinterpret_cast<const float4*>(kpb + kvbase + t * 64);
    #pragma unroll
    for (int i = 0; i < 16; ++i) {
        float4 x = kp4[i];
        kv[4*i+0] = x.x; kv[4*i+1] = x.y; kv[4*i+2] = x.z; kv[4*i+3] = x.w;
    }
    float ckt = ck6[bh * N + t];

    for (int r = 0; r < QBLK; ++r) {
        int n = n0 + r;
        const float* qr = qp + (bh * N + n) * 64;   // uniform -> s_load
        float s = cq6[bh * N + n] + ckt;
        #pragma unroll
        for (int e = 0; e < 64; ++e)
            s = fmaf(w4g[e], fabsf(qr[e] + kv[e]), s);   // abs = free modifier
        if (mask[(b * N + n) * N + t] == 0) s = NEG_INF;

        // per-wave max + sum, single barrier merge
        float m = s;
        #pragma unroll
        for (int off = 32; off > 0; off >>= 1) m = fmaxf(m, __shfl_xor(m, off, 64));
        float p = __expf(s - m);
        float l = p;
        #pragma unroll
        for (int off = 32; off > 0; off >>= 1) l += __shfl_xor(l, off, 64);
        if (lane == 0) red[r & 1][wid] = make_float2(m, l);
        __syncthreads();
        float2 r0 = red[r & 1][0], r1 = red[r & 1][1];
        float2 r2 = red[r & 1][2], r3 = red[r & 1][3];
        float gm = fmaxf(fmaxf(r0.x, r1.x), fmaxf(r2.x, r3.x));
        float gs = r0.y * __expf(r0.x - gm) + r1.y * __expf(r1.x - gm)
                 + r2.y * __expf(r2.x - gm) + r3.y * __expf(r3.x - gm);
        float pn = p * __expf(m - gm) * __frcp_rn(gs);
        smem[r * 256 + t] = pn;
        out[PATTN_OFF + (bh * N + n) * N + t] = pn;
    }
    __syncthreads();

    // PV: thread = (mc=wid, d=lane); V loads coalesced, p via broadcast b128
    float acc[QBLK] = {};
    const float* Vp = V + kvbase + wid * 64 * 64 + lane;
    #pragma unroll 4
    for (int j0 = 0; j0 < 16; ++j0) {
        float v0 = Vp[(4*j0+0) * 64];
        float v1 = Vp[(4*j0+1) * 64];
        float v2 = Vp[(4*j0+2) * 64];
        float v3 = Vp[(4*j0+3) * 64];
        #pragma unroll
        for (int r = 0; r < QBLK; ++r) {
            float4 p4 = *reinterpret_cast<const float4*>(&smem[r * 256 + wid * 64 + 4 * j0]);
            acc[r] = fmaf(p4.x, v0, fmaf(p4.y, v1, fmaf(p4.z, v2, fmaf(p4.w, v3, acc[r]))));
        }
    }
    __syncthreads();
    #pragma unroll
    for (int r = 0; r < QBLK; ++r) smem[wid * 512 + r * 64 + lane] = acc[r];
    __syncthreads();
    #pragma unroll
    for (int h = 0; h < 2; ++h) {
        int r = wid + h * 4;
        float o = smem[0 * 512 + r * 64 + lane] + smem[1 * 512 + r * 64 + lane]
                + smem[2 * 512 + r * 64 + lane] + smem[3 * 512 + r * 64 + lane];
        out[(bh * N + n0 + r) * 64 + lane] = o;
    }
}

extern "C" void kernel_launch(void* const* d_in, const int* in_sizes, int n_in,
                              void* d_out, int out_size, void* d_ws, size_t ws_size,
                              hipStream_t stream) {
    const float* q    = (const float*)d_in[0];
    const float* k    = (const float*)d_in[1];
    const float* v    = (const float*)d_in[2];
    const int*   mask = (const int*)d_in[3];
    const float* W_h  = (const float*)d_in[4];
    const float* b_h  = (const float*)d_in[5];
    const float* W_o  = (const float*)d_in[6];
    const float* b_o  = (const float*)d_in[7];
    float* out = (float*)d_out;

    float* qp  = (float*)d_ws;
    float* kpb = qp + NROWS * 64;
    float* cq6 = kpb + NROWS * 64;
    float* ck6 = cq6 + NROWS;
    float* w4  = ck6 + NROWS;

    proj_kernel<<<NROWS / 32, 256, 0, stream>>>(q, k, W_h, b_h, W_o, b_o, qp, kpb, cq6, ck6, w4);
    attn_kernel<<<B * H * (N / QBLK), 256, 0, stream>>>(qp, kpb, v, mask, cq6, ck6, w4, out);
}

// Round 3
// 54.796 us; speedup vs baseline: 1.6189x; 1.1020x over previous
//
#include <hip/hip_runtime.h>

#define NEG_INF -1000000000.0f

constexpr int B = 4, H = 8, N = 256, D = 64;
constexpr int QBLK = 8;
constexpr int PATTN_OFF = B * H * N * D;   // 524288
constexpr int NROWS = B * H * N;           // 8192

// ws layout (floats): qp[NROWS*64] | kpb[NROWS*64] | cq6[NROWS] | ck6[NROWS] | w4[64]

__global__ __launch_bounds__(256) void proj_kernel(
    const float* __restrict__ q, const float* __restrict__ k,
    const float* __restrict__ W_h, const float* __restrict__ b_h,
    const float* __restrict__ W_o, const float* __restrict__ b_o,
    float* __restrict__ qp, float* __restrict__ kpb,
    float* __restrict__ cq6, float* __restrict__ ck6, float* __restrict__ w4)
{
    __shared__ float WT[128 * 65];   // WT[d][e] = W_h[e][d], stride 65 -> bank (d+e)%32
    int t = threadIdx.x;
    int lane = t & 63;
    int wid = __builtin_amdgcn_readfirstlane(t >> 6);

    #pragma unroll
    for (int i = 0; i < 8; ++i) {
        int fidx = (t + i * 256) * 4;
        float4 w = *reinterpret_cast<const float4*>(W_h + fidx);
        int e = fidx >> 7, d = fidx & 127;
        WT[(d + 0) * 65 + e] = w.x;
        WT[(d + 1) * 65 + e] = w.y;
        WT[(d + 2) * 65 + e] = w.z;
        WT[(d + 3) * 65 + e] = w.w;
    }
    if (blockIdx.x == 0 && t < 64) w4[t] = 0.4f * W_o[t];
    __syncthreads();

    int rbase = blockIdx.x * 16 + wid * 4;   // 4 rows/thread, e = lane
    float accq[4] = {}, acck[4] = {};
    float wq[32], wk[32];
    #pragma unroll
    for (int half = 0; half < 2; ++half) {
        int d0 = half * 32;
        #pragma unroll
        for (int d = 0; d < 32; ++d) {
            wq[d] = WT[(d0 + d) * 65 + lane];
            wk[d] = WT[(64 + d0 + d) * 65 + lane];
        }
        #pragma unroll
        for (int j = 0; j < 4; ++j) {
            const float* qrow = q + (rbase + j) * 64 + d0;   // uniform -> s_load
            const float* krow = k + (rbase + j) * 64 + d0;
            #pragma unroll
            for (int d = 0; d < 32; ++d) {
                accq[j] = fmaf(qrow[d], wq[d], accq[j]);
                acck[j] = fmaf(krow[d], wk[d], acck[j]);
            }
        }
    }
    float bh_e = b_h[lane];
    float wo = W_o[lane];
    float bo = b_o[0];
    #pragma unroll
    for (int j = 0; j < 4; ++j) {
        float aq = accq[j];
        float ak = acck[j] + bh_e;
        qp[(rbase + j) * 64 + lane] = aq;
        kpb[(rbase + j) * 64 + lane] = ak;
        float sq = wo * aq, sk = wo * ak;
        #pragma unroll
        for (int off = 32; off > 0; off >>= 1) {
            sq += __shfl_xor(sq, off, 64);
            sk += __shfl_xor(sk, off, 64);
        }
        if (lane == 0) {
            cq6[rbase + j] = 0.6f * sq + bo;
            ck6[rbase + j] = 0.6f * sk;
        }
    }
}

__global__ __launch_bounds__(256) void attn_kernel(
    const float* __restrict__ qp, const float* __restrict__ kpb,
    const float* __restrict__ V, const int* __restrict__ mask,
    const float* __restrict__ cq6, const float* __restrict__ ck6,
    const float* __restrict__ w4g,
    float* __restrict__ out)
{
    __shared__ float p_s[QBLK * 256];
    __shared__ float pv_s[4 * QBLK * 64];
    __shared__ float2 red[4][QBLK];

    int t = threadIdx.x;
    int lane = t & 63;
    int wid = __builtin_amdgcn_readfirstlane(t >> 6);
    int bh = blockIdx.x >> 5;
    int nb = blockIdx.x & 31;
    int b = bh >> 3;
    int n0 = nb * QBLK;
    int kvbase = bh * N * 64;

    // prefetch mask rows (independent global loads, issued up-front)
    int mv[QBLK];
    #pragma unroll
    for (int r = 0; r < QBLK; ++r)
        mv[r] = mask[(b * N + n0 + r) * N + t];

    // kpb row t -> 64 VGPRs
    float kv[64];
    const float4* kp4 = reinterpret_cast<const float4*>(kpb + kvbase + t * 64);
    #pragma unroll
    for (int i = 0; i < 16; ++i) {
        float4 x = kp4[i];
        kv[4*i+0] = x.x; kv[4*i+1] = x.y; kv[4*i+2] = x.z; kv[4*i+3] = x.w;
    }
    float ckt = ck6[bh * N + t];

    // ---- scores: 8 independent accumulator chains, one pass over e ----
    float s8[QBLK];
    const float* cq = cq6 + bh * N + n0;   // uniform
    #pragma unroll
    for (int r = 0; r < QBLK; ++r) s8[r] = cq[r] + ckt;

    const float* qr = qp + (bh * N + n0) * 64;   // uniform; qr[r*64+e]
    #pragma unroll
    for (int e0 = 0; e0 < 64; e0 += 16) {
        #pragma unroll
        for (int e1 = 0; e1 < 16; ++e1) {
            int e = e0 + e1;
            float kve = kv[e];
            float we = w4g[e];
            #pragma unroll
            for (int r = 0; r < QBLK; ++r)
                s8[r] = fmaf(we, fabsf(qr[r * 64 + e] + kve), s8[r]);
        }
    }
    #pragma unroll
    for (int r = 0; r < QBLK; ++r)
        if (mv[r] == 0) s8[r] = NEG_INF;

    // ---- softmax: per-wave reduce all 8 rows, ONE barrier, merge ----
    float m8[QBLK], p8[QBLK];
    #pragma unroll
    for (int r = 0; r < QBLK; ++r) {
        float m = s8[r];
        #pragma unroll
        for (int off = 32; off > 0; off >>= 1) m = fmaxf(m, __shfl_xor(m, off, 64));
        m8[r] = m;
    }
    #pragma unroll
    for (int r = 0; r < QBLK; ++r) {
        float p = __expf(s8[r] - m8[r]);
        p8[r] = p;
        float l = p;
        #pragma unroll
        for (int off = 32; off > 0; off >>= 1) l += __shfl_xor(l, off, 64);
        if (lane == 0) red[wid][r] = make_float2(m8[r], l);
    }
    __syncthreads();
    #pragma unroll
    for (int r = 0; r < QBLK; ++r) {
        float2 r0 = red[0][r], r1 = red[1][r], r2 = red[2][r], r3 = red[3][r];
        float gm = fmaxf(fmaxf(r0.x, r1.x), fmaxf(r2.x, r3.x));
        float gs = r0.y * __expf(r0.x - gm) + r1.y * __expf(r1.x - gm)
                 + r2.y * __expf(r2.x - gm) + r3.y * __expf(r3.x - gm);
        float pn = p8[r] * __expf(m8[r] - gm) * __frcp_rn(gs);
        p_s[r * 256 + t] = pn;
        out[PATTN_OFF + (bh * N + n0 + r) * N + t] = pn;
    }
    __syncthreads();

    // ---- PV: thread = (mc=wid, d=lane); coalesced V, broadcast p ----
    float acc[QBLK] = {};
    const float* Vp = V + kvbase + wid * 64 * 64 + lane;
    #pragma unroll 4
    for (int j0 = 0; j0 < 16; ++j0) {
        float v0 = Vp[(4*j0+0) * 64];
        float v1 = Vp[(4*j0+1) * 64];
        float v2 = Vp[(4*j0+2) * 64];
        float v3 = Vp[(4*j0+3) * 64];
        #pragma unroll
        for (int r = 0; r < QBLK; ++r) {
            float4 p4 = *reinterpret_cast<const float4*>(&p_s[r * 256 + wid * 64 + 4 * j0]);
            acc[r] = fmaf(p4.x, v0, fmaf(p4.y, v1, fmaf(p4.z, v2, fmaf(p4.w, v3, acc[r]))));
        }
    }
    __syncthreads();
    #pragma unroll
    for (int r = 0; r < QBLK; ++r) pv_s[wid * 512 + r * 64 + lane] = acc[r];
    __syncthreads();
    #pragma unroll
    for (int h = 0; h < 2; ++h) {
        int r = wid + h * 4;
        float o = pv_s[0 * 512 + r * 64 + lane] + pv_s[1 * 512 + r * 64 + lane]
                + pv_s[2 * 512 + r * 64 + lane] + pv_s[3 * 512 + r * 64 + lane];
        out[(bh * N + n0 + r) * 64 + lane] = o;
    }
}

extern "C" void kernel_launch(void* const* d_in, const int* in_sizes, int n_in,
                              void* d_out, int out_size, void* d_ws, size_t ws_size,
                              hipStream_t stream) {
    const float* q    = (const float*)d_in[0];
    const float* k    = (const float*)d_in[1];
    const float* v    = (const float*)d_in[2];
    const int*   mask = (const int*)d_in[3];
    const float* W_h  = (const float*)d_in[4];
    const float* b_h  = (const float*)d_in[5];
    const float* W_o  = (const float*)d_in[6];
    const float* b_o  = (const float*)d_in[7];
    float* out = (float*)d_out;

    float* qp  = (float*)d_ws;
    float* kpb = qp + NROWS * 64;
    float* cq6 = kpb + NROWS * 64;
    float* ck6 = cq6 + NROWS;
    float* w4  = ck6 + NROWS;

    proj_kernel<<<NROWS / 16, 256, 0, stream>>>(q, k, W_h, b_h, W_o, b_o, qp, kpb, cq6, ck6, w4);
    attn_kernel<<<B * H * (N / QBLK), 256, 0, stream>>>(qp, kpb, v, mask, cq6, ck6, w4, out);
}

// Round 4
// 47.938 us; speedup vs baseline: 1.8505x; 1.1431x over previous
//
#include <hip/hip_runtime.h>

#define NEG_INF -1000000000.0f

constexpr int B = 4, H = 8, N = 256, D = 64;
constexpr int QBLK = 8;
constexpr int PATTN_OFF = B * H * N * D;   // 524288
constexpr int NROWS = B * H * N;           // 8192
constexpr int NXCD = 8;

// ws layout (floats): qp[NROWS*64] | kpb[NROWS*64] | cq6[NROWS] | ck6[NROWS] | w4[64]

__global__ __launch_bounds__(256, 4) void proj_kernel(
    const float* __restrict__ q, const float* __restrict__ k,
    const float* __restrict__ W_h, const float* __restrict__ b_h,
    const float* __restrict__ W_o, const float* __restrict__ b_o,
    float* __restrict__ qp, float* __restrict__ kpb,
    float* __restrict__ cq6, float* __restrict__ ck6, float* __restrict__ w4)
{
    __shared__ float WT[128 * 65];   // WT[d][e] = W_h[e][d], stride 65 -> bank (d+e)%32
    int t = threadIdx.x;
    int lane = t & 63;
    int wid = __builtin_amdgcn_readfirstlane(t >> 6);

    // XCD swizzle: 1024 blocks, 8 XCDs -> XCD x owns rows [x*1024, (x+1)*1024)
    int bid = blockIdx.x;
    int work = (bid & 7) * 128 + (bid >> 3);

    #pragma unroll
    for (int i = 0; i < 8; ++i) {
        int fidx = (t + i * 256) * 4;
        float4 w = *reinterpret_cast<const float4*>(W_h + fidx);
        int e = fidx >> 7, d = fidx & 127;
        WT[(d + 0) * 65 + e] = w.x;
        WT[(d + 1) * 65 + e] = w.y;
        WT[(d + 2) * 65 + e] = w.z;
        WT[(d + 3) * 65 + e] = w.w;
    }
    if (bid == 0 && t < 64) w4[t] = 0.4f * W_o[t];
    __syncthreads();

    int rbase = work * 8 + wid * 2;   // 2 rows/thread, e = lane
    float accq[2] = {}, acck[2] = {};
    float wq[32], wk[32];
    #pragma unroll
    for (int half = 0; half < 2; ++half) {
        int d0 = half * 32;
        #pragma unroll
        for (int d = 0; d < 32; ++d) {
            wq[d] = WT[(d0 + d) * 65 + lane];
            wk[d] = WT[(64 + d0 + d) * 65 + lane];
        }
        #pragma unroll
        for (int j = 0; j < 2; ++j) {
            const float* qrow = q + (rbase + j) * 64 + d0;   // wave-uniform -> s_load
            const float* krow = k + (rbase + j) * 64 + d0;
            #pragma unroll
            for (int d = 0; d < 32; ++d) {
                accq[j] = fmaf(qrow[d], wq[d], accq[j]);
                acck[j] = fmaf(krow[d], wk[d], acck[j]);
            }
        }
    }
    float bh_e = b_h[lane];
    float wo = W_o[lane];
    float bo = b_o[0];
    #pragma unroll
    for (int j = 0; j < 2; ++j) {
        float aq = accq[j];
        float ak = acck[j] + bh_e;
        qp[(rbase + j) * 64 + lane] = aq;
        kpb[(rbase + j) * 64 + lane] = ak;
        float sq = wo * aq, sk = wo * ak;
        #pragma unroll
        for (int off = 32; off > 0; off >>= 1) {
            sq += __shfl_xor(sq, off, 64);
            sk += __shfl_xor(sk, off, 64);
        }
        if (lane == 0) {
            cq6[rbase + j] = 0.6f * sq + bo;
            ck6[rbase + j] = 0.6f * sk;
        }
    }
}

__global__ __launch_bounds__(256, 4) void attn_kernel(
    const float* __restrict__ qp, const float* __restrict__ kpb,
    const float* __restrict__ V, const int* __restrict__ mask,
    const float* __restrict__ cq6, const float* __restrict__ ck6,
    const float* __restrict__ w4g,
    float* __restrict__ out)
{
    __shared__ float p_s[QBLK * 256];
    __shared__ float pv_s[4 * QBLK * 64];
    __shared__ float2 red[4][QBLK];

    int t = threadIdx.x;
    int lane = t & 63;
    int wid = __builtin_amdgcn_readfirstlane(t >> 6);

    // XCD swizzle: all 32 blocks of a bh land on the same XCD (1024 = 8*128)
    int bid = blockIdx.x;
    int work = (bid & 7) * 128 + (bid >> 3);
    int bh = work >> 5;
    int nb = work & 31;
    int b = bh >> 3;
    int n0 = nb * QBLK;
    int kvbase = bh * N * 64;

    // kpb row t -> 64 VGPRs (issued first, needed first)
    float kv[64];
    const float4* kp4 = reinterpret_cast<const float4*>(kpb + kvbase + t * 64);
    #pragma unroll
    for (int i = 0; i < 16; ++i) {
        float4 x = kp4[i];
        kv[4*i+0] = x.x; kv[4*i+1] = x.y; kv[4*i+2] = x.z; kv[4*i+3] = x.w;
    }
    // prefetch mask rows
    int mv[QBLK];
    #pragma unroll
    for (int r = 0; r < QBLK; ++r)
        mv[r] = mask[(b * N + n0 + r) * N + t];
    float ckt = ck6[bh * N + t];

    // ---- scores: 8 independent accumulator chains, one pass over e ----
    float s8[QBLK];
    const float* cq = cq6 + bh * N + n0;   // uniform
    #pragma unroll
    for (int r = 0; r < QBLK; ++r) s8[r] = cq[r] + ckt;

    const float* qr = qp + (bh * N + n0) * 64;   // uniform; qr[r*64+e]
    #pragma unroll
    for (int e0 = 0; e0 < 64; e0 += 16) {
        #pragma unroll
        for (int e1 = 0; e1 < 16; ++e1) {
            int e = e0 + e1;
            float kve = kv[e];
            float we = w4g[e];
            #pragma unroll
            for (int r = 0; r < QBLK; ++r)
                s8[r] = fmaf(we, fabsf(qr[r * 64 + e] + kve), s8[r]);
        }
    }
    #pragma unroll
    for (int r = 0; r < QBLK; ++r)
        if (mv[r] == 0) s8[r] = NEG_INF;

    // ---- softmax: per-wave reduce all 8 rows, ONE barrier, merge ----
    float m8[QBLK], p8[QBLK];
    #pragma unroll
    for (int r = 0; r < QBLK; ++r) {
        float m = s8[r];
        #pragma unroll
        for (int off = 32; off > 0; off >>= 1) m = fmaxf(m, __shfl_xor(m, off, 64));
        m8[r] = m;
    }
    #pragma unroll
    for (int r = 0; r < QBLK; ++r) {
        float p = __expf(s8[r] - m8[r]);
        p8[r] = p;
        float l = p;
        #pragma unroll
        for (int off = 32; off > 0; off >>= 1) l += __shfl_xor(l, off, 64);
        if (lane == 0) red[wid][r] = make_float2(m8[r], l);
    }
    __syncthreads();
    #pragma unroll
    for (int r = 0; r < QBLK; ++r) {
        float2 r0 = red[0][r], r1 = red[1][r], r2 = red[2][r], r3 = red[3][r];
        float gm = fmaxf(fmaxf(r0.x, r1.x), fmaxf(r2.x, r3.x));
        float gs = r0.y * __expf(r0.x - gm) + r1.y * __expf(r1.x - gm)
                 + r2.y * __expf(r2.x - gm) + r3.y * __expf(r3.x - gm);
        float pn = p8[r] * __expf(m8[r] - gm) * __frcp_rn(gs);
        p_s[r * 256 + t] = pn;
        out[PATTN_OFF + (bh * N + n0 + r) * N + t] = pn;
    }
    __syncthreads();

    // ---- PV: thread = (mc=wid, d=lane); coalesced V, broadcast p ----
    float acc[QBLK] = {};
    const float* Vp = V + kvbase + wid * 64 * 64 + lane;
    #pragma unroll
    for (int j0 = 0; j0 < 16; ++j0) {
        float v0 = Vp[(4*j0+0) * 64];
        float v1 = Vp[(4*j0+1) * 64];
        float v2 = Vp[(4*j0+2) * 64];
        float v3 = Vp[(4*j0+3) * 64];
        #pragma unroll
        for (int r = 0; r < QBLK; ++r) {
            float4 p4 = *reinterpret_cast<const float4*>(&p_s[r * 256 + wid * 64 + 4 * j0]);
            acc[r] = fmaf(p4.x, v0, fmaf(p4.y, v1, fmaf(p4.z, v2, fmaf(p4.w, v3, acc[r]))));
        }
    }
    __syncthreads();
    #pragma unroll
    for (int r = 0; r < QBLK; ++r) pv_s[wid * 512 + r * 64 + lane] = acc[r];
    __syncthreads();
    #pragma unroll
    for (int h = 0; h < 2; ++h) {
        int r = wid + h * 4;
        float o = pv_s[0 * 512 + r * 64 + lane] + pv_s[1 * 512 + r * 64 + lane]
                + pv_s[2 * 512 + r * 64 + lane] + pv_s[3 * 512 + r * 64 + lane];
        out[(bh * N + n0 + r) * 64 + lane] = o;
    }
}

extern "C" void kernel_launch(void* const* d_in, const int* in_sizes, int n_in,
                              void* d_out, int out_size, void* d_ws, size_t ws_size,
                              hipStream_t stream) {
    const float* q    = (const float*)d_in[0];
    const float* k    = (const float*)d_in[1];
    const float* v    = (const float*)d_in[2];
    const int*   mask = (const int*)d_in[3];
    const float* W_h  = (const float*)d_in[4];
    const float* b_h  = (const float*)d_in[5];
    const float* W_o  = (const float*)d_in[6];
    const float* b_o  = (const float*)d_in[7];
    float* out = (float*)d_out;

    float* qp  = (float*)d_ws;
    float* kpb = qp + NROWS * 64;
    float* cq6 = kpb + NROWS * 64;
    float* ck6 = cq6 + NROWS;
    float* w4  = ck6 + NROWS;

    proj_kernel<<<NROWS / 8, 256, 0, stream>>>(q, k, W_h, b_h, W_o, b_o, qp, kpb, cq6, ck6, w4);
    attn_kernel<<<B * H * (N / QBLK), 256, 0, stream>>>(qp, kpb, v, mask, cq6, ck6, w4, out);
}